// Round 4
// baseline (423.760 us; speedup 1.0000x reference)
//
#include <hip/hip_runtime.h>

#define N_NODES 50000
#define N_EDGES 800000
#define C 128
#define NPB 16  // nodes per block in layer1 (50000 % 16 == 0 -> 3125 blocks)

// ---------------- degree histogram (int) ----------------
__global__ void hist_kernel(const int* __restrict__ dst, int* __restrict__ deg) {
    int e = blockIdx.x * blockDim.x + threadIdx.x;
    if (e < N_EDGES) atomicAdd(&deg[dst[e]], 1);
}

// ---------------- exclusive scan of deg -> row_ptr (single block) ----------------
__global__ __launch_bounds__(256) void scan_kernel(const int* __restrict__ deg,
                                                   int* __restrict__ row_ptr) {
    __shared__ int sums[256];
    const int PER = (N_NODES + 255) / 256;  // 196
    int t = threadIdx.x;
    int base = t * PER;
    int s = 0;
    for (int i = 0; i < PER; i++) {
        int idx = base + i;
        if (idx < N_NODES) s += deg[idx];
    }
    sums[t] = s;
    __syncthreads();
    for (int off = 1; off < 256; off <<= 1) {
        int v = (t >= off) ? sums[t - off] : 0;
        __syncthreads();
        sums[t] += v;
        __syncthreads();
    }
    int run = (t == 0) ? 0 : sums[t - 1];
    for (int i = 0; i < PER; i++) {
        int idx = base + i;
        if (idx < N_NODES) { row_ptr[idx] = run; run += deg[idx]; }
    }
    if (t == 255) row_ptr[N_NODES] = run;
}

// ---------------- bucket fill: esorted[row_ptr[d] + pos] = src ----------------
__global__ void bucket_kernel(const int* __restrict__ src, const int* __restrict__ dst,
                              const int* __restrict__ row_ptr, int* __restrict__ cursor,
                              int* __restrict__ esorted) {
    int e = blockIdx.x * blockDim.x + threadIdx.x;
    if (e < N_EDGES) {
        int d = dst[e];
        int pos = atomicAdd(&cursor[d], 1);
        esorted[row_ptr[d] + pos] = src[e];
    }
}

// ---------------- W transpose: WT[c][k] = W[k][c] ----------------
__global__ void transpose_w(const float* __restrict__ W1l, const float* __restrict__ W1r,
                            float* __restrict__ WTl, float* __restrict__ WTr) {
    int k = blockIdx.x;
    int c = threadIdx.x;
    WTl[c * C + k] = W1l[k * C + c];
    WTr[c * C + k] = W1r[k * C + c];
}

__device__ __forceinline__ void acc4(float4& a, const float4 v) {
    a.x += v.x; a.y += v.y; a.z += v.z; a.w += v.w;
}

// gather mean of feat rows listed in esorted[start..start+d), this thread's float4 slice q
__device__ __forceinline__ float4 gather_mean(const float* __restrict__ feat,
                                              const int* __restrict__ esorted,
                                              int start, int d, int q) {
    float4 a0 = {0,0,0,0}, a1 = {0,0,0,0}, a2 = {0,0,0,0}, a3 = {0,0,0,0};
    int e = 0;
    for (; e + 4 <= d; e += 4) {
        int s0 = esorted[start + e + 0];
        int s1 = esorted[start + e + 1];
        int s2 = esorted[start + e + 2];
        int s3 = esorted[start + e + 3];
        float4 v0 = ((const float4*)(feat + (size_t)s0 * C))[q];
        float4 v1 = ((const float4*)(feat + (size_t)s1 * C))[q];
        float4 v2 = ((const float4*)(feat + (size_t)s2 * C))[q];
        float4 v3 = ((const float4*)(feat + (size_t)s3 * C))[q];
        acc4(a0, v0); acc4(a1, v1); acc4(a2, v2); acc4(a3, v3);
    }
    for (; e < d; e++) {
        int s = esorted[start + e];
        acc4(a0, ((const float4*)(feat + (size_t)s * C))[q]);
    }
    float inv = 1.0f / fmaxf((float)d, 1.0f);
    float4 m;
    m.x = (a0.x + a1.x + a2.x + a3.x) * inv;
    m.y = (a0.y + a1.y + a2.y + a3.y) * inv;
    m.z = (a0.z + a1.z + a2.z + a3.z) * inv;
    m.w = (a0.w + a1.w + a2.w + a3.w) * inv;
    return m;
}

// ---------------- layer 1 fused: gather-mean + h = relu(mean@W1l + b1l + x@W1r) ----------------
// Gather: 32 threads/row (float4/lane), 4 rows concurrent, 4 passes (16 nodes).
// GEMM: thread c owns output column c; W pre-transposed so W reads are per-thread float4;
// ms/xs read as broadcast ds_read_b128.
__global__ __launch_bounds__(128) void layer1_fused(
    const float* __restrict__ x, const int* __restrict__ row_ptr,
    const int* __restrict__ deg, const int* __restrict__ esorted,
    const float* __restrict__ WTl, const float* __restrict__ b1l,
    const float* __restrict__ WTr, float* __restrict__ h) {
    __shared__ float xs[NPB][C];
    __shared__ float ms[NPB][C];
    int t = threadIdx.x;
    int n0 = blockIdx.x * NPB;
    int rq = t >> 5;     // row slot 0..3
    int q  = t & 31;     // float4 index within row
    #pragma unroll
    for (int g = 0; g < NPB / 4; g++) {
        int n = g * 4 + rq;
        int node = n0 + n;
        ((float4*)xs[n])[q] = ((const float4*)(x + (size_t)node * C))[q];
        ((float4*)ms[n])[q] = gather_mean(x, esorted, row_ptr[node], deg[node], q);
    }
    __syncthreads();
    int c = t;
    float bias = b1l[c];
    float acc[NPB];
    #pragma unroll
    for (int n = 0; n < NPB; n++) acc[n] = bias;
    const float4* wtl = (const float4*)(WTl + (size_t)c * C);  // contiguous per thread
    const float4* wtr = (const float4*)(WTr + (size_t)c * C);
    for (int k4 = 0; k4 < C / 4; k4++) {
        float4 wl = wtl[k4];
        float4 wr = wtr[k4];
        #pragma unroll
        for (int n = 0; n < NPB; n++) {
            float4 m4 = ((const float4*)ms[n])[k4];   // broadcast
            float4 x4 = ((const float4*)xs[n])[k4];   // broadcast
            float a = acc[n];
            a = fmaf(m4.x, wl.x, a); a = fmaf(x4.x, wr.x, a);
            a = fmaf(m4.y, wl.y, a); a = fmaf(x4.y, wr.y, a);
            a = fmaf(m4.z, wl.z, a); a = fmaf(x4.z, wr.z, a);
            a = fmaf(m4.w, wl.w, a); a = fmaf(x4.w, wr.w, a);
            acc[n] = a;
        }
    }
    #pragma unroll
    for (int n = 0; n < NPB; n++)
        h[(size_t)(n0 + n) * C + c] = fmaxf(acc[n], 0.0f);
}

// ---------------- z/r: z = h@W2l, out = h@W2r + b2l (pre-aggregation transform) ----------------
// one wave per node; W2l/W2r (128,2) row-major -> lane loads float4 covering k=2*lane..2*lane+1
__global__ __launch_bounds__(256) void z_kernel(
    const float* __restrict__ h, const float* __restrict__ W2l,
    const float* __restrict__ W2r, const float* __restrict__ b2l,
    float* __restrict__ z, float* __restrict__ out) {
    int lane = threadIdx.x & 63;
    int w = threadIdx.x >> 6;
    int node = blockIdx.x * 4 + w;   // 50000 % 4 == 0
    float2 hv = ((const float2*)(h + (size_t)node * C))[lane];
    float4 l4 = ((const float4*)W2l)[lane];
    float4 r4 = ((const float4*)W2r)[lane];
    float z0 = hv.x * l4.x + hv.y * l4.z;
    float z1 = hv.x * l4.y + hv.y * l4.w;
    float r0 = hv.x * r4.x + hv.y * r4.z;
    float r1 = hv.x * r4.y + hv.y * r4.w;
    #pragma unroll
    for (int off = 32; off > 0; off >>= 1) {
        z0 += __shfl_down(z0, off);
        z1 += __shfl_down(z1, off);
        r0 += __shfl_down(r0, off);
        r1 += __shfl_down(r1, off);
    }
    if (lane == 0) {
        z[node * 2 + 0] = z0;
        z[node * 2 + 1] = z1;
        out[node * 2 + 0] = r0 + b2l[0];
        out[node * 2 + 1] = r1 + b2l[1];
    }
}

// ---------------- final: out[n] += mean_{j in N(n)} z[j] ----------------
__global__ void final_kernel(const float* __restrict__ z, const int* __restrict__ row_ptr,
                             const int* __restrict__ deg, const int* __restrict__ esorted,
                             float* __restrict__ out) {
    int n = blockIdx.x * blockDim.x + threadIdx.x;
    if (n >= N_NODES) return;
    int start = row_ptr[n];
    int d = deg[n];
    float a0 = 0, a1 = 0, b0 = 0, b1 = 0;
    int e = 0;
    for (; e + 2 <= d; e += 2) {
        int s0 = esorted[start + e];
        int s1 = esorted[start + e + 1];
        float2 v0 = ((const float2*)z)[s0];
        float2 v1 = ((const float2*)z)[s1];
        a0 += v0.x; a1 += v0.y; b0 += v1.x; b1 += v1.y;
    }
    if (e < d) {
        float2 v = ((const float2*)z)[esorted[start + e]];
        a0 += v.x; a1 += v.y;
    }
    float inv = 1.0f / fmaxf((float)d, 1.0f);
    out[n * 2 + 0] += (a0 + b0) * inv;
    out[n * 2 + 1] += (a1 + b1) * inv;
}

extern "C" void kernel_launch(void* const* d_in, const int* in_sizes, int n_in,
                              void* d_out, int out_size, void* d_ws, size_t ws_size,
                              hipStream_t stream) {
    const float* x   = (const float*)d_in[0];
    const int*   ei  = (const int*)d_in[1];   // (2, 800000) row-major
    const float* W1l = (const float*)d_in[2];
    const float* b1l = (const float*)d_in[3];
    const float* W1r = (const float*)d_in[4];
    const float* W2l = (const float*)d_in[5];
    const float* b2l = (const float*)d_in[6];
    const float* W2r = (const float*)d_in[7];
    float* out = (float*)d_out;

    const int* src = ei;
    const int* dst = ei + N_EDGES;

    // workspace layout (4-byte units):
    // deg[50000] | cursor[50000] | row_ptr[50112] | esorted[800000] |
    // WTl[16384] | WTr[16384] | z[100000] | h[6.4M]
    int* deg     = (int*)d_ws;
    int* cursor  = deg + 50000;
    int* row_ptr = cursor + 50000;
    int* esorted = row_ptr + 50112;
    float* WTl   = (float*)(esorted + N_EDGES);
    float* WTr   = WTl + C * C;
    float* z     = WTr + C * C;
    float* h     = z + 2 * N_NODES;

    hipMemsetAsync(deg, 0, 50000 * sizeof(int), stream);
    hipMemsetAsync(cursor, 0, 50000 * sizeof(int), stream);

    hist_kernel<<<(N_EDGES + 255) / 256, 256, 0, stream>>>(dst, deg);
    transpose_w<<<C, C, 0, stream>>>(W1l, W1r, WTl, WTr);
    scan_kernel<<<1, 256, 0, stream>>>(deg, row_ptr);
    bucket_kernel<<<(N_EDGES + 255) / 256, 256, 0, stream>>>(src, dst, row_ptr, cursor, esorted);

    layer1_fused<<<N_NODES / NPB, 128, 0, stream>>>(
        x, row_ptr, deg, esorted, WTl, b1l, WTr, h);
    z_kernel<<<N_NODES / 4, 256, 0, stream>>>(h, W2l, W2r, b2l, z, out);
    final_kernel<<<(N_NODES + 255) / 256, 256, 0, stream>>>(z, row_ptr, deg, esorted, out);
}

// Round 5
// 298.539 us; speedup vs baseline: 1.4194x; 1.4194x over previous
//
#include <hip/hip_runtime.h>

#define N_NODES 50000
#define N_EDGES 800000
#define C 128
#define NPB 8          // nodes per block in layer1 (50000 % 8 == 0 -> 6250 blocks)
#define SCAN_B 196     // ceil(50000/256)

// ---------------- degree histogram (int) ----------------
__global__ void hist_kernel(const int* __restrict__ dst, int* __restrict__ deg) {
    int e = blockIdx.x * blockDim.x + threadIdx.x;
    if (e < N_EDGES) atomicAdd(&deg[dst[e]], 1);
}

// ---------------- scan A: per-block sums of deg ----------------
__global__ __launch_bounds__(256) void scanA_kernel(const int* __restrict__ deg,
                                                    int* __restrict__ bsum) {
    __shared__ int red[4];
    int i = blockIdx.x * 256 + threadIdx.x;
    int v = (i < N_NODES) ? deg[i] : 0;
    #pragma unroll
    for (int off = 32; off > 0; off >>= 1) v += __shfl_down(v, off);
    int lane = threadIdx.x & 63, wid = threadIdx.x >> 6;
    if (lane == 0) red[wid] = v;
    __syncthreads();
    if (threadIdx.x == 0) bsum[blockIdx.x] = red[0] + red[1] + red[2] + red[3];
}

// ---------------- scan B: exclusive scan of bsum[SCAN_B] (single small block) ----------------
__global__ __launch_bounds__(256) void scanB_kernel(const int* __restrict__ bsum,
                                                    int* __restrict__ boff) {
    __shared__ int sums[256];
    int t = threadIdx.x;
    int orig = (t < SCAN_B) ? bsum[t] : 0;
    sums[t] = orig;
    __syncthreads();
    for (int off = 1; off < 256; off <<= 1) {
        int v = (t >= off) ? sums[t - off] : 0;
        __syncthreads();
        sums[t] += v;
        __syncthreads();
    }
    if (t < SCAN_B) boff[t] = sums[t] - orig;   // exclusive
}

// ---------------- scan C: row_ptr[i] = boff[b] + exclusive_scan_in_block(deg); cursor=row_ptr ----------------
__global__ __launch_bounds__(256) void scanC_kernel(const int* __restrict__ deg,
                                                    const int* __restrict__ boff,
                                                    int* __restrict__ row_ptr,
                                                    int* __restrict__ cursor) {
    __shared__ int sums[256];
    int t = threadIdx.x;
    int i = blockIdx.x * 256 + t;
    int v = (i < N_NODES) ? deg[i] : 0;
    sums[t] = v;
    __syncthreads();
    for (int off = 1; off < 256; off <<= 1) {
        int u = (t >= off) ? sums[t - off] : 0;
        __syncthreads();
        sums[t] += u;
        __syncthreads();
    }
    if (i < N_NODES) {
        int p = boff[blockIdx.x] + sums[t] - v;   // exclusive
        row_ptr[i] = p;
        cursor[i]  = p;
    }
}

// ---------------- bucket fill: esorted[atomicAdd(cursor[d])] = src ----------------
__global__ __launch_bounds__(256) void bucket_kernel(const int* __restrict__ src,
                                                     const int* __restrict__ dst,
                                                     int* __restrict__ cursor,
                                                     int* __restrict__ esorted) {
    int e = blockIdx.x * blockDim.x + threadIdx.x;
    if (e < N_EDGES) {
        int d = dst[e];
        int pos = atomicAdd(&cursor[d], 1);   // absolute position (cursor initialized to row_ptr)
        esorted[pos] = src[e];
    }
}

__device__ __forceinline__ void acc4(float4& a, const float4 v) {
    a.x += v.x; a.y += v.y; a.z += v.z; a.w += v.w;
}

// gather mean of feat rows listed in esorted[start..start+d), this thread's float4 slice q
__device__ __forceinline__ float4 gather_mean(const float* __restrict__ feat,
                                              const int* __restrict__ esorted,
                                              int start, int d, int q) {
    float4 a0 = {0,0,0,0}, a1 = {0,0,0,0}, a2 = {0,0,0,0}, a3 = {0,0,0,0};
    int e = 0;
    for (; e + 4 <= d; e += 4) {
        int s0 = esorted[start + e + 0];
        int s1 = esorted[start + e + 1];
        int s2 = esorted[start + e + 2];
        int s3 = esorted[start + e + 3];
        float4 v0 = ((const float4*)(feat + (size_t)s0 * C))[q];
        float4 v1 = ((const float4*)(feat + (size_t)s1 * C))[q];
        float4 v2 = ((const float4*)(feat + (size_t)s2 * C))[q];
        float4 v3 = ((const float4*)(feat + (size_t)s3 * C))[q];
        acc4(a0, v0); acc4(a1, v1); acc4(a2, v2); acc4(a3, v3);
    }
    for (; e < d; e++) {
        int s = esorted[start + e];
        acc4(a0, ((const float4*)(feat + (size_t)s * C))[q]);
    }
    float inv = 1.0f / fmaxf((float)d, 1.0f);
    float4 m;
    m.x = (a0.x + a1.x + a2.x + a3.x) * inv;
    m.y = (a0.y + a1.y + a2.y + a3.y) * inv;
    m.z = (a0.z + a1.z + a2.z + a3.z) * inv;
    m.w = (a0.w + a1.w + a2.w + a3.w) * inv;
    return m;
}

// ---------------- layer 1 fused + layer 2 linear epilogue ----------------
// h = relu(mean@W1l + b1l + x@W1r) computed in registers (never materialized);
// epilogue emits z = h@W2l (for post-gather mean, by linearity) and
// out = h@W2r + b2l (root term of layer 2).
__global__ __launch_bounds__(128) void layer1_fused(
    const float* __restrict__ x, const int* __restrict__ row_ptr,
    const int* __restrict__ deg, const int* __restrict__ esorted,
    const float* __restrict__ W1l, const float* __restrict__ b1l,
    const float* __restrict__ W1r, const float* __restrict__ W2l,
    const float* __restrict__ W2r, const float* __restrict__ b2l,
    float* __restrict__ z, float* __restrict__ out) {
    __shared__ float xs[NPB][C];
    __shared__ float ms[NPB][C];
    __shared__ float red[NPB][2][4];
    int t = threadIdx.x;
    int n0 = blockIdx.x * NPB;
    int rq = t >> 5;     // row slot 0..3
    int q  = t & 31;     // float4 index within row
    #pragma unroll
    for (int g = 0; g < NPB / 4; g++) {
        int n = g * 4 + rq;
        int node = n0 + n;
        ((float4*)xs[n])[q] = ((const float4*)(x + (size_t)node * C))[q];
        ((float4*)ms[n])[q] = gather_mean(x, esorted, row_ptr[node], deg[node], q);
    }
    __syncthreads();
    int c = t;
    float bias = b1l[c];
    float acc[NPB];
    #pragma unroll
    for (int n = 0; n < NPB; n++) acc[n] = bias;
    for (int k = 0; k < C; k++) {
        float wl = W1l[k * C + c];   // coalesced across threads
        float wr = W1r[k * C + c];
        #pragma unroll
        for (int n = 0; n < NPB; n++)
            acc[n] = fmaf(ms[n][k], wl, fmaf(xs[n][k], wr, acc[n]));
    }
    // epilogue: per-column layer-2 weights, reduce across the 128 columns
    float w2l0 = W2l[c * 2 + 0], w2l1 = W2l[c * 2 + 1];
    float w2r0 = W2r[c * 2 + 0], w2r1 = W2r[c * 2 + 1];
    int lane = t & 63, wid = t >> 6;
    #pragma unroll
    for (int n = 0; n < NPB; n++) {
        float v = fmaxf(acc[n], 0.0f);   // relu(h)
        float z0 = v * w2l0, z1 = v * w2l1;
        float r0 = v * w2r0, r1 = v * w2r1;
        #pragma unroll
        for (int off = 32; off > 0; off >>= 1) {
            z0 += __shfl_down(z0, off);
            z1 += __shfl_down(z1, off);
            r0 += __shfl_down(r0, off);
            r1 += __shfl_down(r1, off);
        }
        if (lane == 0) {
            red[n][wid][0] = z0; red[n][wid][1] = z1;
            red[n][wid][2] = r0; red[n][wid][3] = r1;
        }
    }
    __syncthreads();
    if (t < NPB) {
        int node = n0 + t;
        z[node * 2 + 0]   = red[t][0][0] + red[t][1][0];
        z[node * 2 + 1]   = red[t][0][1] + red[t][1][1];
        out[node * 2 + 0] = red[t][0][2] + red[t][1][2] + b2l[0];
        out[node * 2 + 1] = red[t][0][3] + red[t][1][3] + b2l[1];
    }
}

// ---------------- final: out[n] += mean_{j in N(n)} z[j] ----------------
__global__ void final_kernel(const float* __restrict__ z, const int* __restrict__ row_ptr,
                             const int* __restrict__ deg, const int* __restrict__ esorted,
                             float* __restrict__ out) {
    int n = blockIdx.x * blockDim.x + threadIdx.x;
    if (n >= N_NODES) return;
    int start = row_ptr[n];
    int d = deg[n];
    float a0 = 0, a1 = 0, b0 = 0, b1 = 0;
    int e = 0;
    for (; e + 2 <= d; e += 2) {
        int s0 = esorted[start + e];
        int s1 = esorted[start + e + 1];
        float2 v0 = ((const float2*)z)[s0];
        float2 v1 = ((const float2*)z)[s1];
        a0 += v0.x; a1 += v0.y; b0 += v1.x; b1 += v1.y;
    }
    if (e < d) {
        float2 v = ((const float2*)z)[esorted[start + e]];
        a0 += v.x; a1 += v.y;
    }
    float inv = 1.0f / fmaxf((float)d, 1.0f);
    out[n * 2 + 0] += (a0 + b0) * inv;
    out[n * 2 + 1] += (a1 + b1) * inv;
}

extern "C" void kernel_launch(void* const* d_in, const int* in_sizes, int n_in,
                              void* d_out, int out_size, void* d_ws, size_t ws_size,
                              hipStream_t stream) {
    const float* x   = (const float*)d_in[0];
    const int*   ei  = (const int*)d_in[1];   // (2, 800000) row-major
    const float* W1l = (const float*)d_in[2];
    const float* b1l = (const float*)d_in[3];
    const float* W1r = (const float*)d_in[4];
    const float* W2l = (const float*)d_in[5];
    const float* b2l = (const float*)d_in[6];
    const float* W2r = (const float*)d_in[7];
    float* out = (float*)d_out;

    const int* src = ei;
    const int* dst = ei + N_EDGES;

    // workspace layout (4-byte units):
    // deg[50000] | cursor[50000] | row_ptr[50048] | esorted[800000] |
    // bsum[256] | boff[256] | z[100000]
    int* deg     = (int*)d_ws;
    int* cursor  = deg + 50000;
    int* row_ptr = cursor + 50000;
    int* esorted = row_ptr + 50048;
    int* bsum    = esorted + N_EDGES;
    int* boff    = bsum + 256;
    float* z     = (float*)(boff + 256);

    hipMemsetAsync(deg, 0, 50000 * sizeof(int), stream);

    hist_kernel<<<(N_EDGES + 255) / 256, 256, 0, stream>>>(dst, deg);
    scanA_kernel<<<SCAN_B, 256, 0, stream>>>(deg, bsum);
    scanB_kernel<<<1, 256, 0, stream>>>(bsum, boff);
    scanC_kernel<<<SCAN_B, 256, 0, stream>>>(deg, boff, row_ptr, cursor);
    bucket_kernel<<<(N_EDGES + 255) / 256, 256, 0, stream>>>(src, dst, cursor, esorted);

    layer1_fused<<<N_NODES / NPB, 128, 0, stream>>>(
        x, row_ptr, deg, esorted, W1l, b1l, W1r, W2l, W2r, b2l, z, out);
    final_kernel<<<(N_NODES + 255) / 256, 256, 0, stream>>>(z, row_ptr, deg, esorted, out);
}

// Round 6
// 289.962 us; speedup vs baseline: 1.4614x; 1.0296x over previous
//
#include <hip/hip_runtime.h>

#define N_NODES 50000
#define N_EDGES 800000
#define C 128
#define NPB 8          // nodes per block in layer1 (50000 % 8 == 0 -> 6250 blocks)
#define SCAN_B 196     // ceil(50000/256)

// ---------------- degree histogram: 4 edges per thread ----------------
__global__ __launch_bounds__(256) void hist_kernel(const int* __restrict__ dst,
                                                   int* __restrict__ deg) {
    int i = blockIdx.x * blockDim.x + threadIdx.x;
    if (i < N_EDGES / 4) {
        int4 d = ((const int4*)dst)[i];
        atomicAdd(&deg[d.x], 1);
        atomicAdd(&deg[d.y], 1);
        atomicAdd(&deg[d.z], 1);
        atomicAdd(&deg[d.w], 1);
    }
}

// ---------------- scan A: per-block sums of deg ----------------
__global__ __launch_bounds__(256) void scanA_kernel(const int* __restrict__ deg,
                                                    int* __restrict__ bsum) {
    __shared__ int red[4];
    int i = blockIdx.x * 256 + threadIdx.x;
    int v = (i < N_NODES) ? deg[i] : 0;
    #pragma unroll
    for (int off = 32; off > 0; off >>= 1) v += __shfl_down(v, off);
    int lane = threadIdx.x & 63, wid = threadIdx.x >> 6;
    if (lane == 0) red[wid] = v;
    __syncthreads();
    if (threadIdx.x == 0) bsum[blockIdx.x] = red[0] + red[1] + red[2] + red[3];
}

// ---------------- scan B: exclusive scan of bsum[SCAN_B] ----------------
__global__ __launch_bounds__(256) void scanB_kernel(const int* __restrict__ bsum,
                                                    int* __restrict__ boff) {
    __shared__ int sums[256];
    int t = threadIdx.x;
    int orig = (t < SCAN_B) ? bsum[t] : 0;
    sums[t] = orig;
    __syncthreads();
    for (int off = 1; off < 256; off <<= 1) {
        int v = (t >= off) ? sums[t - off] : 0;
        __syncthreads();
        sums[t] += v;
        __syncthreads();
    }
    if (t < SCAN_B) boff[t] = sums[t] - orig;   // exclusive
}

// ---------------- scan C: row_ptr + cursor init ----------------
__global__ __launch_bounds__(256) void scanC_kernel(const int* __restrict__ deg,
                                                    const int* __restrict__ boff,
                                                    int* __restrict__ row_ptr,
                                                    int* __restrict__ cursor) {
    __shared__ int sums[256];
    int t = threadIdx.x;
    int i = blockIdx.x * 256 + t;
    int v = (i < N_NODES) ? deg[i] : 0;
    sums[t] = v;
    __syncthreads();
    for (int off = 1; off < 256; off <<= 1) {
        int u = (t >= off) ? sums[t - off] : 0;
        __syncthreads();
        sums[t] += u;
        __syncthreads();
    }
    if (i < N_NODES) {
        int p = boff[blockIdx.x] + sums[t] - v;   // exclusive
        row_ptr[i] = p;
        cursor[i]  = p;
    }
    if (blockIdx.x == 0 && t == 0) row_ptr[N_NODES] = N_EDGES;  // sentinel
}

// ---------------- bucket fill: 4 edges per thread ----------------
__global__ __launch_bounds__(256) void bucket_kernel(const int* __restrict__ src,
                                                     const int* __restrict__ dst,
                                                     int* __restrict__ cursor,
                                                     int* __restrict__ esorted) {
    int i = blockIdx.x * blockDim.x + threadIdx.x;
    if (i < N_EDGES / 4) {
        int4 s = ((const int4*)src)[i];
        int4 d = ((const int4*)dst)[i];
        int p0 = atomicAdd(&cursor[d.x], 1);
        int p1 = atomicAdd(&cursor[d.y], 1);
        int p2 = atomicAdd(&cursor[d.z], 1);
        int p3 = atomicAdd(&cursor[d.w], 1);
        esorted[p0] = s.x;
        esorted[p1] = s.y;
        esorted[p2] = s.z;
        esorted[p3] = s.w;
    }
}

__device__ __forceinline__ void acc4(float4& a, const float4 v) {
    a.x += v.x; a.y += v.y; a.z += v.z; a.w += v.w;
}

// gather mean of feat rows listed in esorted[start..start+d), this thread's float4 slice q
__device__ __forceinline__ float4 gather_mean(const float* __restrict__ feat,
                                              const int* __restrict__ esorted,
                                              int start, int d, int q) {
    float4 a0 = {0,0,0,0}, a1 = {0,0,0,0}, a2 = {0,0,0,0}, a3 = {0,0,0,0};
    int e = 0;
    for (; e + 4 <= d; e += 4) {
        int s0 = esorted[start + e + 0];
        int s1 = esorted[start + e + 1];
        int s2 = esorted[start + e + 2];
        int s3 = esorted[start + e + 3];
        float4 v0 = ((const float4*)(feat + (size_t)s0 * C))[q];
        float4 v1 = ((const float4*)(feat + (size_t)s1 * C))[q];
        float4 v2 = ((const float4*)(feat + (size_t)s2 * C))[q];
        float4 v3 = ((const float4*)(feat + (size_t)s3 * C))[q];
        acc4(a0, v0); acc4(a1, v1); acc4(a2, v2); acc4(a3, v3);
    }
    for (; e < d; e++) {
        int s = esorted[start + e];
        acc4(a0, ((const float4*)(feat + (size_t)s * C))[q]);
    }
    float inv = 1.0f / fmaxf((float)d, 1.0f);
    float4 m;
    m.x = (a0.x + a1.x + a2.x + a3.x) * inv;
    m.y = (a0.y + a1.y + a2.y + a3.y) * inv;
    m.z = (a0.z + a1.z + a2.z + a3.z) * inv;
    m.w = (a0.w + a1.w + a2.w + a3.w) * inv;
    return m;
}

// ---------------- layer 1 fused + layer 2 linear epilogue ----------------
// h = relu(mean@W1l + b1l + x@W1r) in registers (never materialized);
// epilogue: z = h@W2l (aggregated later by linearity), out = h@W2r + b2l.
__global__ __launch_bounds__(128) void layer1_fused(
    const float* __restrict__ x, const int* __restrict__ row_ptr,
    const int* __restrict__ esorted,
    const float* __restrict__ W1l, const float* __restrict__ b1l,
    const float* __restrict__ W1r, const float* __restrict__ W2l,
    const float* __restrict__ W2r, const float* __restrict__ b2l,
    float* __restrict__ z, float* __restrict__ out) {
    __shared__ float xs[NPB][C];
    __shared__ float ms[NPB][C];
    __shared__ float red[NPB][2][4];
    int t = threadIdx.x;
    int n0 = blockIdx.x * NPB;
    int rq = t >> 5;     // row slot 0..3
    int q  = t & 31;     // float4 index within row
    #pragma unroll
    for (int g = 0; g < NPB / 4; g++) {
        int n = g * 4 + rq;
        int node = n0 + n;
        int start = row_ptr[node];
        int d = row_ptr[node + 1] - start;
        ((float4*)xs[n])[q] = ((const float4*)(x + (size_t)node * C))[q];
        ((float4*)ms[n])[q] = gather_mean(x, esorted, start, d, q);
    }
    __syncthreads();
    int c = t;
    float bias = b1l[c];
    float acc[NPB];
    #pragma unroll
    for (int n = 0; n < NPB; n++) acc[n] = bias;
    const float* wl_col = W1l + c;   // column c, coalesced across threads
    const float* wr_col = W1r + c;
    for (int k4 = 0; k4 < C / 4; k4++) {
        int k = k4 * 4;
        float wl0 = wl_col[(k + 0) * C], wl1 = wl_col[(k + 1) * C];
        float wl2 = wl_col[(k + 2) * C], wl3 = wl_col[(k + 3) * C];
        float wr0 = wr_col[(k + 0) * C], wr1 = wr_col[(k + 1) * C];
        float wr2 = wr_col[(k + 2) * C], wr3 = wr_col[(k + 3) * C];
        #pragma unroll
        for (int n = 0; n < NPB; n++) {
            float4 m4 = ((const float4*)ms[n])[k4];   // ds_read_b128 broadcast
            float4 x4 = ((const float4*)xs[n])[k4];
            float a = acc[n];
            a = fmaf(m4.x, wl0, a); a = fmaf(x4.x, wr0, a);
            a = fmaf(m4.y, wl1, a); a = fmaf(x4.y, wr1, a);
            a = fmaf(m4.z, wl2, a); a = fmaf(x4.z, wr2, a);
            a = fmaf(m4.w, wl3, a); a = fmaf(x4.w, wr3, a);
            acc[n] = a;
        }
    }
    // epilogue: per-column layer-2 weights, reduce across the 128 columns
    float w2l0 = W2l[c * 2 + 0], w2l1 = W2l[c * 2 + 1];
    float w2r0 = W2r[c * 2 + 0], w2r1 = W2r[c * 2 + 1];
    int lane = t & 63, wid = t >> 6;
    #pragma unroll
    for (int n = 0; n < NPB; n++) {
        float v = fmaxf(acc[n], 0.0f);   // relu(h)
        float z0 = v * w2l0, z1 = v * w2l1;
        float r0 = v * w2r0, r1 = v * w2r1;
        #pragma unroll
        for (int off = 32; off > 0; off >>= 1) {
            z0 += __shfl_down(z0, off);
            z1 += __shfl_down(z1, off);
            r0 += __shfl_down(r0, off);
            r1 += __shfl_down(r1, off);
        }
        if (lane == 0) {
            red[n][wid][0] = z0; red[n][wid][1] = z1;
            red[n][wid][2] = r0; red[n][wid][3] = r1;
        }
    }
    __syncthreads();
    if (t < NPB) {
        int node = n0 + t;
        z[node * 2 + 0]   = red[t][0][0] + red[t][1][0];
        z[node * 2 + 1]   = red[t][0][1] + red[t][1][1];
        out[node * 2 + 0] = red[t][0][2] + red[t][1][2] + b2l[0];
        out[node * 2 + 1] = red[t][0][3] + red[t][1][3] + b2l[1];
    }
}

// ---------------- final: out[n] += mean_{j in N(n)} z[j], 16 lanes per node ----------------
__global__ __launch_bounds__(256) void final_kernel(const float* __restrict__ z,
                                                    const int* __restrict__ row_ptr,
                                                    const int* __restrict__ esorted,
                                                    float* __restrict__ out) {
    int t = threadIdx.x;
    int sub = t & 15;
    int node = blockIdx.x * 16 + (t >> 4);   // 50000 % 16 == 0 -> 3125 blocks
    int start = row_ptr[node];
    int d = row_ptr[node + 1] - start;
    float a0 = 0.0f, a1 = 0.0f;
    for (int e = sub; e < d; e += 16) {
        float2 v = ((const float2*)z)[esorted[start + e]];
        a0 += v.x; a1 += v.y;
    }
    #pragma unroll
    for (int off = 8; off > 0; off >>= 1) {
        a0 += __shfl_down(a0, off);
        a1 += __shfl_down(a1, off);
    }
    if (sub == 0) {
        float inv = 1.0f / fmaxf((float)d, 1.0f);
        out[node * 2 + 0] += a0 * inv;
        out[node * 2 + 1] += a1 * inv;
    }
}

extern "C" void kernel_launch(void* const* d_in, const int* in_sizes, int n_in,
                              void* d_out, int out_size, void* d_ws, size_t ws_size,
                              hipStream_t stream) {
    const float* x   = (const float*)d_in[0];
    const int*   ei  = (const int*)d_in[1];   // (2, 800000) row-major
    const float* W1l = (const float*)d_in[2];
    const float* b1l = (const float*)d_in[3];
    const float* W1r = (const float*)d_in[4];
    const float* W2l = (const float*)d_in[5];
    const float* b2l = (const float*)d_in[6];
    const float* W2r = (const float*)d_in[7];
    float* out = (float*)d_out;

    const int* src = ei;
    const int* dst = ei + N_EDGES;

    // workspace layout (4-byte units):
    // deg[50000] | cursor[50000] | row_ptr[50048] | esorted[800000] |
    // bsum[256] | boff[256] | z[100000]
    int* deg     = (int*)d_ws;
    int* cursor  = deg + 50000;
    int* row_ptr = cursor + 50000;
    int* esorted = row_ptr + 50048;
    int* bsum    = esorted + N_EDGES;
    int* boff    = bsum + 256;
    float* z     = (float*)(boff + 256);

    hipMemsetAsync(deg, 0, 50000 * sizeof(int), stream);

    hist_kernel<<<(N_EDGES / 4 + 255) / 256, 256, 0, stream>>>(dst, deg);
    scanA_kernel<<<SCAN_B, 256, 0, stream>>>(deg, bsum);
    scanB_kernel<<<1, 256, 0, stream>>>(bsum, boff);
    scanC_kernel<<<SCAN_B, 256, 0, stream>>>(deg, boff, row_ptr, cursor);
    bucket_kernel<<<(N_EDGES / 4 + 255) / 256, 256, 0, stream>>>(src, dst, cursor, esorted);

    layer1_fused<<<N_NODES / NPB, 128, 0, stream>>>(
        x, row_ptr, esorted, W1l, b1l, W1r, W2l, W2r, b2l, z, out);
    final_kernel<<<N_NODES / 16, 256, 0, stream>>>(z, row_ptr, esorted, out);
}

// Round 7
// 281.658 us; speedup vs baseline: 1.5045x; 1.0295x over previous
//
#include <hip/hip_runtime.h>

#define N_NODES 50000
#define N_EDGES 800000
#define C 128
#define NPB 8          // nodes per block in layer1 (50000 % 8 == 0 -> 6250 blocks)
#define SCAN_B 196     // ceil(50000/256)

typedef unsigned short ushort_t;
typedef unsigned int uint_t;

// ---------------- fp32 -> bf16 (RNE) copy of x ----------------
__device__ __forceinline__ ushort_t f2bf(float f) {
    uint_t u = __float_as_uint(f);
    u += 0x7fffu + ((u >> 16) & 1u);
    return (ushort_t)(u >> 16);
}

__global__ __launch_bounds__(256) void tobf16_kernel(const float* __restrict__ x,
                                                     ushort_t* __restrict__ xh) {
    int i = blockIdx.x * 256 + threadIdx.x;   // one float4 per thread; 6.4M/4 = 1.6M threads
    float4 v = ((const float4*)x)[i];
    ushort4 o;
    o.x = f2bf(v.x); o.y = f2bf(v.y); o.z = f2bf(v.z); o.w = f2bf(v.w);
    ((ushort4*)xh)[i] = o;
}

// ---------------- degree histogram: 4 edges per thread ----------------
__global__ __launch_bounds__(256) void hist_kernel(const int* __restrict__ dst,
                                                   int* __restrict__ deg) {
    int i = blockIdx.x * blockDim.x + threadIdx.x;
    if (i < N_EDGES / 4) {
        int4 d = ((const int4*)dst)[i];
        atomicAdd(&deg[d.x], 1);
        atomicAdd(&deg[d.y], 1);
        atomicAdd(&deg[d.z], 1);
        atomicAdd(&deg[d.w], 1);
    }
}

// ---------------- scan A: per-block sums of deg ----------------
__global__ __launch_bounds__(256) void scanA_kernel(const int* __restrict__ deg,
                                                    int* __restrict__ bsum) {
    __shared__ int red[4];
    int i = blockIdx.x * 256 + threadIdx.x;
    int v = (i < N_NODES) ? deg[i] : 0;
    #pragma unroll
    for (int off = 32; off > 0; off >>= 1) v += __shfl_down(v, off);
    int lane = threadIdx.x & 63, wid = threadIdx.x >> 6;
    if (lane == 0) red[wid] = v;
    __syncthreads();
    if (threadIdx.x == 0) bsum[blockIdx.x] = red[0] + red[1] + red[2] + red[3];
}

// ---------------- scan B: exclusive scan of bsum[SCAN_B] ----------------
__global__ __launch_bounds__(256) void scanB_kernel(const int* __restrict__ bsum,
                                                    int* __restrict__ boff) {
    __shared__ int sums[256];
    int t = threadIdx.x;
    int orig = (t < SCAN_B) ? bsum[t] : 0;
    sums[t] = orig;
    __syncthreads();
    for (int off = 1; off < 256; off <<= 1) {
        int v = (t >= off) ? sums[t - off] : 0;
        __syncthreads();
        sums[t] += v;
        __syncthreads();
    }
    if (t < SCAN_B) boff[t] = sums[t] - orig;   // exclusive
}

// ---------------- scan C: row_ptr + cursor init ----------------
__global__ __launch_bounds__(256) void scanC_kernel(const int* __restrict__ deg,
                                                    const int* __restrict__ boff,
                                                    int* __restrict__ row_ptr,
                                                    int* __restrict__ cursor) {
    __shared__ int sums[256];
    int t = threadIdx.x;
    int i = blockIdx.x * 256 + t;
    int v = (i < N_NODES) ? deg[i] : 0;
    sums[t] = v;
    __syncthreads();
    for (int off = 1; off < 256; off <<= 1) {
        int u = (t >= off) ? sums[t - off] : 0;
        __syncthreads();
        sums[t] += u;
        __syncthreads();
    }
    if (i < N_NODES) {
        int p = boff[blockIdx.x] + sums[t] - v;   // exclusive
        row_ptr[i] = p;
        cursor[i]  = p;
    }
    if (blockIdx.x == 0 && t == 0) row_ptr[N_NODES] = N_EDGES;  // sentinel
}

// ---------------- bucket fill: 4 edges per thread ----------------
__global__ __launch_bounds__(256) void bucket_kernel(const int* __restrict__ src,
                                                     const int* __restrict__ dst,
                                                     int* __restrict__ cursor,
                                                     int* __restrict__ esorted) {
    int i = blockIdx.x * blockDim.x + threadIdx.x;
    if (i < N_EDGES / 4) {
        int4 s = ((const int4*)src)[i];
        int4 d = ((const int4*)dst)[i];
        int p0 = atomicAdd(&cursor[d.x], 1);
        int p1 = atomicAdd(&cursor[d.y], 1);
        int p2 = atomicAdd(&cursor[d.z], 1);
        int p3 = atomicAdd(&cursor[d.w], 1);
        esorted[p0] = s.x;
        esorted[p1] = s.y;
        esorted[p2] = s.z;
        esorted[p3] = s.w;
    }
}

// accumulate 8 bf16 (packed in uint4) into a[0..7] (fp32)
__device__ __forceinline__ void bf8_acc(float* a, const uint4 v) {
    a[0] += __uint_as_float(v.x << 16);
    a[1] += __uint_as_float(v.x & 0xffff0000u);
    a[2] += __uint_as_float(v.y << 16);
    a[3] += __uint_as_float(v.y & 0xffff0000u);
    a[4] += __uint_as_float(v.z << 16);
    a[5] += __uint_as_float(v.z & 0xffff0000u);
    a[6] += __uint_as_float(v.w << 16);
    a[7] += __uint_as_float(v.w & 0xffff0000u);
}

// ---------------- layer 1 fused + layer 2 linear epilogue ----------------
// Gather (bf16): 16 lanes per row (uint4 = 8 bf16/lane), 8 nodes concurrently
// in ONE pass (slot = t>>4). Accumulate fp32, ILP-4, indices broadcast.
// GEMM: h = relu(mean@W1l + b1l + x@W1r) in registers; epilogue emits
// z = h@W2l (aggregated later by linearity) and out = h@W2r + b2l.
__global__ __launch_bounds__(128) void layer1_fused(
    const float* __restrict__ x, const ushort_t* __restrict__ xh,
    const int* __restrict__ row_ptr, const int* __restrict__ esorted,
    const float* __restrict__ W1l, const float* __restrict__ b1l,
    const float* __restrict__ W1r, const float* __restrict__ W2l,
    const float* __restrict__ W2r, const float* __restrict__ b2l,
    float* __restrict__ z, float* __restrict__ out) {
    __shared__ float xs[NPB][C];
    __shared__ float ms[NPB][C];
    __shared__ float red[NPB][2][4];
    int t = threadIdx.x;
    int n0 = blockIdx.x * NPB;

    // ---- stage xs (fp32, coalesced): 32 lanes/row, 4 rows/pass, 2 passes ----
    {
        int rq = t >> 5, q32 = t & 31;
        #pragma unroll
        for (int g = 0; g < 2; g++) {
            int n = g * 4 + rq;
            ((float4*)xs[n])[q32] = ((const float4*)(x + (size_t)(n0 + n) * C))[q32];
        }
    }

    // ---- gather mean (bf16): slot = t>>4 owns node n0+slot; q = t&15 ----
    {
        int slot = t >> 4, q = t & 15;
        int node = n0 + slot;
        int start = row_ptr[node];
        int d = row_ptr[node + 1] - start;
        float a[8] = {0,0,0,0,0,0,0,0};
        float b[8] = {0,0,0,0,0,0,0,0};
        int e = 0;
        for (; e + 4 <= d; e += 4) {
            int s0 = esorted[start + e + 0];
            int s1 = esorted[start + e + 1];
            int s2 = esorted[start + e + 2];
            int s3 = esorted[start + e + 3];
            uint4 v0 = ((const uint4*)(xh + (size_t)s0 * C))[q];
            uint4 v1 = ((const uint4*)(xh + (size_t)s1 * C))[q];
            uint4 v2 = ((const uint4*)(xh + (size_t)s2 * C))[q];
            uint4 v3 = ((const uint4*)(xh + (size_t)s3 * C))[q];
            bf8_acc(a, v0); bf8_acc(b, v1); bf8_acc(a, v2); bf8_acc(b, v3);
        }
        for (; e < d; e++) {
            uint4 v = ((const uint4*)(xh + (size_t)esorted[start + e] * C))[q];
            bf8_acc(a, v);
        }
        float inv = 1.0f / fmaxf((float)d, 1.0f);
        float* mrow = &ms[slot][q * 8];
        #pragma unroll
        for (int i = 0; i < 8; i++) mrow[i] = (a[i] + b[i]) * inv;
    }
    __syncthreads();

    // ---- GEMM: thread c owns output column c across the 8 nodes ----
    int c = t;
    float bias = b1l[c];
    float acc[NPB];
    #pragma unroll
    for (int n = 0; n < NPB; n++) acc[n] = bias;
    const float* wl_col = W1l + c;   // column c, coalesced across threads
    const float* wr_col = W1r + c;
    for (int k4 = 0; k4 < C / 4; k4++) {
        int k = k4 * 4;
        float wl0 = wl_col[(k + 0) * C], wl1 = wl_col[(k + 1) * C];
        float wl2 = wl_col[(k + 2) * C], wl3 = wl_col[(k + 3) * C];
        float wr0 = wr_col[(k + 0) * C], wr1 = wr_col[(k + 1) * C];
        float wr2 = wr_col[(k + 2) * C], wr3 = wr_col[(k + 3) * C];
        #pragma unroll
        for (int n = 0; n < NPB; n++) {
            float4 m4 = ((const float4*)ms[n])[k4];   // ds_read_b128 broadcast
            float4 x4 = ((const float4*)xs[n])[k4];
            float a = acc[n];
            a = fmaf(m4.x, wl0, a); a = fmaf(x4.x, wr0, a);
            a = fmaf(m4.y, wl1, a); a = fmaf(x4.y, wr1, a);
            a = fmaf(m4.z, wl2, a); a = fmaf(x4.z, wr2, a);
            a = fmaf(m4.w, wl3, a); a = fmaf(x4.w, wr3, a);
            acc[n] = a;
        }
    }

    // ---- epilogue: layer-2 linear, reduce across the 128 columns ----
    float w2l0 = W2l[c * 2 + 0], w2l1 = W2l[c * 2 + 1];
    float w2r0 = W2r[c * 2 + 0], w2r1 = W2r[c * 2 + 1];
    int lane = t & 63, wid = t >> 6;
    #pragma unroll
    for (int n = 0; n < NPB; n++) {
        float v = fmaxf(acc[n], 0.0f);   // relu(h)
        float z0 = v * w2l0, z1 = v * w2l1;
        float r0 = v * w2r0, r1 = v * w2r1;
        #pragma unroll
        for (int off = 32; off > 0; off >>= 1) {
            z0 += __shfl_down(z0, off);
            z1 += __shfl_down(z1, off);
            r0 += __shfl_down(r0, off);
            r1 += __shfl_down(r1, off);
        }
        if (lane == 0) {
            red[n][wid][0] = z0; red[n][wid][1] = z1;
            red[n][wid][2] = r0; red[n][wid][3] = r1;
        }
    }
    __syncthreads();
    if (t < NPB) {
        int node = n0 + t;
        z[node * 2 + 0]   = red[t][0][0] + red[t][1][0];
        z[node * 2 + 1]   = red[t][0][1] + red[t][1][1];
        out[node * 2 + 0] = red[t][0][2] + red[t][1][2] + b2l[0];
        out[node * 2 + 1] = red[t][0][3] + red[t][1][3] + b2l[1];
    }
}

// ---------------- final: out[n] += mean_{j in N(n)} z[j], 16 lanes per node ----------------
__global__ __launch_bounds__(256) void final_kernel(const float* __restrict__ z,
                                                    const int* __restrict__ row_ptr,
                                                    const int* __restrict__ esorted,
                                                    float* __restrict__ out) {
    int t = threadIdx.x;
    int sub = t & 15;
    int node = blockIdx.x * 16 + (t >> 4);   // 50000 % 16 == 0 -> 3125 blocks
    int start = row_ptr[node];
    int d = row_ptr[node + 1] - start;
    float a0 = 0.0f, a1 = 0.0f;
    for (int e = sub; e < d; e += 16) {
        float2 v = ((const float2*)z)[esorted[start + e]];
        a0 += v.x; a1 += v.y;
    }
    #pragma unroll
    for (int off = 8; off > 0; off >>= 1) {
        a0 += __shfl_down(a0, off);
        a1 += __shfl_down(a1, off);
    }
    if (sub == 0) {
        float inv = 1.0f / fmaxf((float)d, 1.0f);
        out[node * 2 + 0] += a0 * inv;
        out[node * 2 + 1] += a1 * inv;
    }
}

extern "C" void kernel_launch(void* const* d_in, const int* in_sizes, int n_in,
                              void* d_out, int out_size, void* d_ws, size_t ws_size,
                              hipStream_t stream) {
    const float* x   = (const float*)d_in[0];
    const int*   ei  = (const int*)d_in[1];   // (2, 800000) row-major
    const float* W1l = (const float*)d_in[2];
    const float* b1l = (const float*)d_in[3];
    const float* W1r = (const float*)d_in[4];
    const float* W2l = (const float*)d_in[5];
    const float* b2l = (const float*)d_in[6];
    const float* W2r = (const float*)d_in[7];
    float* out = (float*)d_out;

    const int* src = ei;
    const int* dst = ei + N_EDGES;

    // workspace layout (4-byte units):
    // deg[50000] | cursor[50000] | row_ptr[50048] | esorted[800000] |
    // bsum[256] | boff[256] | z[100000] | xh (6.4M ushort = 3.2M words)
    int* deg     = (int*)d_ws;
    int* cursor  = deg + 50000;
    int* row_ptr = cursor + 50000;
    int* esorted = row_ptr + 50048;
    int* bsum    = esorted + N_EDGES;
    int* boff    = bsum + 256;
    float* z     = (float*)(boff + 256);
    ushort_t* xh = (ushort_t*)(z + 2 * N_NODES);

    hipMemsetAsync(deg, 0, 50000 * sizeof(int), stream);

    tobf16_kernel<<<(N_NODES * C / 4) / 256, 256, 0, stream>>>(x, xh);
    hist_kernel<<<(N_EDGES / 4 + 255) / 256, 256, 0, stream>>>(dst, deg);
    scanA_kernel<<<SCAN_B, 256, 0, stream>>>(deg, bsum);
    scanB_kernel<<<1, 256, 0, stream>>>(bsum, boff);
    scanC_kernel<<<SCAN_B, 256, 0, stream>>>(deg, boff, row_ptr, cursor);
    bucket_kernel<<<(N_EDGES / 4 + 255) / 256, 256, 0, stream>>>(src, dst, cursor, esorted);

    layer1_fused<<<N_NODES / NPB, 128, 0, stream>>>(
        x, xh, row_ptr, esorted, W1l, b1l, W1r, W2l, W2r, b2l, z, out);
    final_kernel<<<N_NODES / 16, 256, 0, stream>>>(z, row_ptr, esorted, out);
}